// Round 3
// baseline (227.229 us; speedup 1.0000x reference)
//
#include <hip/hip_runtime.h>
#include <cstddef>

#define ALPHA 0.2f
constexpr int B = 2, N = 8192, F = 256, D = 128;
constexpr int M = B * N;
constexpr int NB = 2048;          // value buckets per batch
constexpr int SUB = 256;          // elements per sub-block for stable scatter
constexpr int P = N / SUB;        // 32 sub-blocks per batch
constexpr int GB = 8;             // buckets per k_bsum block
constexpr int NBB = NB / GB;      // 256 bsum blocks per batch
constexpr int GSZ = 64;           // buckets per scan group
constexpr int NGRP = NB / GSZ;    // 32 groups per batch

// ---- monotone float<->uint encoding for atomic min/max ----
__device__ inline unsigned fenc(float x) {
  unsigned u = __float_as_uint(x);
  return (u & 0x80000000u) ? ~u : (u | 0x80000000u);
}
__device__ inline float fdec(unsigned u) {
  return (u & 0x80000000u) ? __uint_as_float(u ^ 0x80000000u) : __uint_as_float(~u);
}
__device__ inline void bparams(const unsigned* __restrict__ mmu, int b, float& mn, float& scale) {
  mn = fdec(mmu[b * 2 + 0]);
  float mx = fdec(mmu[b * 2 + 1]);
  float range = mx - mn;
  scale = ((float)NB - 0.001f) / fmaxf(range, 1e-30f);
}
__device__ inline int bucket_of(float x, float mn, float scale) {
  int g = (int)((x - mn) * scale);
  return g < 0 ? 0 : (g > NB - 1 ? NB - 1 : g);
}

// ---------------- GEMM: fts[m][d] = sum_f seq[m][f] * Wf[f][d] ----------------
__global__ __launch_bounds__(256) void k_gemm(const float* __restrict__ seq,
                                              const float* __restrict__ Wf,
                                              float* __restrict__ fts,
                                              unsigned* __restrict__ mmu) {
  if (blockIdx.x == 0 && threadIdx.x < 2 * B) {
    mmu[threadIdx.x] = (threadIdx.x & 1) ? 0u : 0xFFFFFFFFu;  // seed max / min
  }
  __shared__ float As[64][36];
  __shared__ float Bs[32][128];
  const int m0 = blockIdx.x * 64;
  const int t = threadIdx.x;
  const int colg = t & 31;
  const int rowg = t >> 5;
  float acc[8][4];
#pragma unroll
  for (int r = 0; r < 8; ++r)
#pragma unroll
    for (int c = 0; c < 4; ++c) acc[r][c] = 0.f;

  for (int kc = 0; kc < F; kc += 32) {
#pragma unroll
    for (int it = 0; it < 2; ++it) {
      int f = t + it * 256;
      int row = f >> 3, wi = f & 7;
      const float4 v = *reinterpret_cast<const float4*>(
          &seq[(size_t)(m0 + row) * F + kc + wi * 4]);
      As[row][wi * 4 + 0] = v.x; As[row][wi * 4 + 1] = v.y;
      As[row][wi * 4 + 2] = v.z; As[row][wi * 4 + 3] = v.w;
    }
#pragma unroll
    for (int it = 0; it < 4; ++it) {
      int f = t + it * 256;
      int row = f >> 5, c4 = f & 31;
      *reinterpret_cast<float4*>(&Bs[row][c4 * 4]) =
          *reinterpret_cast<const float4*>(&Wf[(size_t)(kc + row) * D + c4 * 4]);
    }
    __syncthreads();
#pragma unroll
    for (int k = 0; k < 32; ++k) {
      float4 b4 = *reinterpret_cast<const float4*>(&Bs[k][colg * 4]);
#pragma unroll
      for (int r = 0; r < 8; ++r) {
        float a = As[rowg * 8 + r][k];
        acc[r][0] += a * b4.x; acc[r][1] += a * b4.y;
        acc[r][2] += a * b4.z; acc[r][3] += a * b4.w;
      }
    }
    __syncthreads();
  }
#pragma unroll
  for (int r = 0; r < 8; ++r) {
    float4 v = {acc[r][0], acc[r][1], acc[r][2], acc[r][3]};
    *reinterpret_cast<float4*>(&fts[(size_t)(m0 + rowg * 8 + r) * D + colg * 4]) = v;
  }
}

// ---------------- f1/f2 + fused per-batch min/max of f2 ----------------
__global__ __launch_bounds__(256) void k_f1f2(const float* __restrict__ fts,
                                              const float* __restrict__ w1,
                                              const float* __restrict__ b1,
                                              const float* __restrict__ w2,
                                              const float* __restrict__ b2,
                                              float* __restrict__ f1,
                                              float* __restrict__ f2,
                                              unsigned* __restrict__ mmu) {
  __shared__ unsigned redmn[4], redmx[4];
  const int wid = threadIdx.x >> 6;
  const int lane = threadIdx.x & 63;
  const int row = blockIdx.x * 4 + wid;
  const float* p = &fts[(size_t)row * D];
  float x0 = p[lane], x1 = p[lane + 64];
  float d1 = x0 * w1[lane] + x1 * w1[lane + 64];
  float d2 = x0 * w2[lane] + x1 * w2[lane + 64];
#pragma unroll
  for (int off = 32; off > 0; off >>= 1) {
    d1 += __shfl_down(d1, off);
    d2 += __shfl_down(d2, off);
  }
  if (lane == 0) {
    f1[row] = d1 + b1[0];
    float v2 = d2 + b2[0];
    f2[row] = v2;
    unsigned e = fenc(v2);
    redmn[wid] = e; redmx[wid] = e;
  }
  __syncthreads();
  if (threadIdx.x == 0) {
    unsigned mn = min(min(redmn[0], redmn[1]), min(redmn[2], redmn[3]));
    unsigned mx = max(max(redmx[0], redmx[1]), max(redmx[2], redmx[3]));
    const int b = row / N;   // block's 4 rows never straddle a batch (N % 4 == 0)
    atomicMin(&mmu[b * 2 + 0], mn);
    atomicMax(&mmu[b * 2 + 1], mx);
  }
}

// ---------------- per-sub-block histogram (deterministic) ----------------
__global__ __launch_bounds__(256) void k_hist(const float* __restrict__ f2,
                                              const unsigned* __restrict__ mmu,
                                              int* __restrict__ bid,
                                              int* __restrict__ histcnt) {
  __shared__ int hist[NB];
  const int b = blockIdx.x / P, p = blockIdx.x % P;
  const int t = threadIdx.x;
  for (int i = t; i < NB; i += 256) hist[i] = 0;
  float mn, scale; bparams(mmu, b, mn, scale);
  const int j = p * SUB + t;
  float x = f2[b * N + j];
  int g = bucket_of(x, mn, scale);
  bid[b * N + j] = g;
  __syncthreads();
  atomicAdd(&hist[g], 1);
  __syncthreads();
  for (int i = t; i < NB; i += 256)
    histcnt[((size_t)(b * P + p)) * NB + i] = hist[i];
}

// ---------------- bucket-count reduce + exclusive Blelloch scan ----------------
__global__ __launch_bounds__(1024) void k_bscan(const int* __restrict__ histcnt,
                                                int* __restrict__ bstart) {
  __shared__ int s[NB];
  const int b = blockIdx.x, t = threadIdx.x;
  int c0 = 0, c1 = 0;
  const int g0 = 2 * t, g1 = 2 * t + 1;
  for (int p = 0; p < P; ++p) {
    const int* h = &histcnt[((size_t)(b * P + p)) * NB];
    c0 += h[g0]; c1 += h[g1];
  }
  s[g0] = c0; s[g1] = c1;
  int offset = 1;
  for (int d = NB >> 1; d > 0; d >>= 1) {
    __syncthreads();
    if (t < d) { int ai = offset * (2 * t + 1) - 1, bi = offset * (2 * t + 2) - 1; s[bi] += s[ai]; }
    offset <<= 1;
  }
  __syncthreads();
  if (t == 0) { bstart[b * (NB + 1) + NB] = s[NB - 1]; s[NB - 1] = 0; }
  for (int d = 1; d < NB; d <<= 1) {
    offset >>= 1;
    __syncthreads();
    if (t < d) {
      int ai = offset * (2 * t + 1) - 1, bi = offset * (2 * t + 2) - 1;
      int tmp = s[ai]; s[ai] = s[bi]; s[bi] += tmp;
    }
  }
  __syncthreads();
  bstart[b * (NB + 1) + g0] = s[g0];
  bstart[b * (NB + 1) + g1] = s[g1];
}

// ---------------- stable deterministic scatter + weight precompute ----------------
__global__ __launch_bounds__(256) void k_scatter(const float* __restrict__ f2,
                                                 const int* __restrict__ bid,
                                                 const int* __restrict__ histcnt,
                                                 const int* __restrict__ bstart,
                                                 float* __restrict__ f2s,
                                                 int* __restrict__ idxs,
                                                 float* __restrict__ wps,
                                                 float* __restrict__ wns) {
  __shared__ int bids[SUB];
  const int b = blockIdx.x / P, p = blockIdx.x % P;
  const int t = threadIdx.x;
  const int j = p * SUB + t;
  const int g = bid[b * N + j];
  bids[t] = g;
  __syncthreads();
  int off = bstart[b * (NB + 1) + g];
  for (int pp = 0; pp < p; ++pp) off += histcnt[((size_t)(b * P + pp)) * NB + g];
  for (int jj = 0; jj < t; ++jj) off += (bids[jj] == g);
  const float x = f2[b * N + j];
  f2s[b * N + off] = x;
  idxs[b * N + off] = j;
  wps[b * N + off] = expf(x);
  wns[b * N + off] = expf(ALPHA * x);
}

// ---------------- per-bucket weighted sums (segmented, deterministic) ----------------
__global__ __launch_bounds__(128) void k_bsum(const float* __restrict__ fts,
                                              const int* __restrict__ idxs,
                                              const float* __restrict__ wps,
                                              const float* __restrict__ wns,
                                              const int* __restrict__ bstart,
                                              float* __restrict__ Wp, float* __restrict__ Wn,
                                              float* __restrict__ Cp, float* __restrict__ Cn) {
  const int b = blockIdx.x / NBB, blk = blockIdx.x % NBB;
  const int d = threadIdx.x;
  const int gbase = blk * GB;
  for (int gg = 0; gg < GB; ++gg) {
    const int g = gbase + gg;
    const int e0 = bstart[b * (NB + 1) + g], e1 = bstart[b * (NB + 1) + g + 1];
    float ap = 0.f, an = 0.f, sp = 0.f, sn = 0.f;
    for (int e = e0; e < e1; ++e) {
      const int j = idxs[b * N + e];
      const float v = fts[((size_t)b * N + j) * D + d];
      const float wp = wps[b * N + e], wn = wns[b * N + e];
      ap += wp * v; an += wn * v; sp += wp; sn += wn;
    }
    Wp[((size_t)b * NB + g) * D + d] = ap;
    Wn[((size_t)b * NB + g) * D + d] = an;
    if (d == 0) { Cp[b * NB + g] = sp; Cn[b * NB + g] = sn; }
  }
}

// ---------------- group sums (64 buckets per group) ----------------
__global__ __launch_bounds__(128) void k_gsumA(const float* __restrict__ Wp, const float* __restrict__ Wn,
                                               const float* __restrict__ Cp, const float* __restrict__ Cn,
                                               float* __restrict__ Gp, float* __restrict__ Gn,
                                               float* __restrict__ SGp, float* __restrict__ SGn) {
  const int b = blockIdx.x / NGRP, grp = blockIdx.x % NGRP;
  const int d = threadIdx.x;
  float sp = 0.f, sn = 0.f, cp = 0.f, cn = 0.f;
  for (int gg = 0; gg < GSZ; ++gg) {
    const int g = grp * GSZ + gg;
    sp += Wp[((size_t)b * NB + g) * D + d];
    sn += Wn[((size_t)b * NB + g) * D + d];
    if (d == 0) { cp += Cp[b * NB + g]; cn += Cn[b * NB + g]; }
  }
  Gp[((size_t)b * NGRP + grp) * D + d] = sp;
  Gn[((size_t)b * NGRP + grp) * D + d] = sn;
  if (d == 0) { SGp[b * NGRP + grp] = cp; SGn[b * NGRP + grp] = cn; }
}

// ---------------- scan the 32 group sums (exclusive prefix neg / suffix pos) ----------------
__global__ __launch_bounds__(128) void k_gscanB(float* __restrict__ Gp, float* __restrict__ Gn,
                                                float* __restrict__ SGp, float* __restrict__ SGn) {
  const int b = blockIdx.x, d = threadIdx.x;
  float run = 0.f;
  for (int grp = 0; grp < NGRP; ++grp) {
    float t = Gn[((size_t)b * NGRP + grp) * D + d];
    Gn[((size_t)b * NGRP + grp) * D + d] = run; run += t;
  }
  run = 0.f;
  for (int grp = NGRP - 1; grp >= 0; --grp) {
    float t = Gp[((size_t)b * NGRP + grp) * D + d];
    Gp[((size_t)b * NGRP + grp) * D + d] = run; run += t;
  }
  if (d == 0) {
    float r = 0.f;
    for (int grp = 0; grp < NGRP; ++grp) { float t = SGn[b * NGRP + grp]; SGn[b * NGRP + grp] = r; r += t; }
    r = 0.f;
    for (int grp = NGRP - 1; grp >= 0; --grp) { float t = SGp[b * NGRP + grp]; SGp[b * NGRP + grp] = r; r += t; }
  }
}

// ---------------- within-group exclusive scans -> bucket-boundary sums ----------------
__global__ __launch_bounds__(128) void k_gscanC(const float* __restrict__ Wp, const float* __restrict__ Wn,
                                                const float* __restrict__ Cp, const float* __restrict__ Cn,
                                                const float* __restrict__ Gp, const float* __restrict__ Gn,
                                                const float* __restrict__ SGp, const float* __restrict__ SGn,
                                                float* __restrict__ BPos, float* __restrict__ BNeg,
                                                float* __restrict__ CpB, float* __restrict__ CnB) {
  const int b = blockIdx.x / NGRP, grp = blockIdx.x % NGRP;
  const int d = threadIdx.x;
  float runn = Gn[((size_t)b * NGRP + grp) * D + d];
  for (int gg = 0; gg < GSZ; ++gg) {
    const int g = grp * GSZ + gg;
    BNeg[((size_t)b * NB + g) * D + d] = runn;
    runn += Wn[((size_t)b * NB + g) * D + d];
  }
  float runp = Gp[((size_t)b * NGRP + grp) * D + d];
  for (int gg = GSZ - 1; gg >= 0; --gg) {
    const int g = grp * GSZ + gg;
    BPos[((size_t)b * NB + g) * D + d] = runp;
    runp += Wp[((size_t)b * NB + g) * D + d];
  }
  if (d == 0) {
    float r = SGn[b * NGRP + grp];
    for (int gg = 0; gg < GSZ; ++gg) { const int g = grp * GSZ + gg; CnB[b * NB + g] = r; r += Cn[b * NB + g]; }
    r = SGp[b * NGRP + grp];
    for (int gg = GSZ - 1; gg >= 0; --gg) { const int g = grp * GSZ + gg; CpB[b * NB + g] = r; r += Cp[b * NB + g]; }
  }
}

// ---------------- query: bucket lookup + boundary resolve + combine ----------------
__global__ __launch_bounds__(128) void k_query(const float* __restrict__ f1,
                                               const float* __restrict__ f2s,
                                               const int* __restrict__ idxs,
                                               const float* __restrict__ wps,
                                               const float* __restrict__ wns,
                                               const float* __restrict__ fts,
                                               const int* __restrict__ bstart,
                                               const unsigned* __restrict__ mmu,
                                               const float* __restrict__ BPos, const float* __restrict__ BNeg,
                                               const float* __restrict__ CpB, const float* __restrict__ CnB,
                                               const float* __restrict__ bias,
                                               float* __restrict__ out) {
  const int row = blockIdx.x;  // b*N + i
  const int b = row / N;
  const int d = threadIdx.x;
  const float f1v = f1[row];
  const float th = -f1v;
  float mn, scale; bparams(mmu, b, mn, scale);
  const int g = bucket_of(th, mn, scale);
  const int base = bstart[b * (NB + 1) + g];
  const int end  = bstart[b * (NB + 1) + g + 1];
  float sn = BNeg[((size_t)b * NB + g) * D + d];
  float sp = BPos[((size_t)b * NB + g) * D + d];
  float cn = CnB[b * NB + g];
  float cp = CpB[b * NB + g];
  for (int e = base; e < end; ++e) {
    const float key = f2s[b * N + e];
    const int j = idxs[b * N + e];
    const float v = fts[((size_t)b * N + j) * D + d];
    if (key <= th) { const float w = wns[b * N + e]; sn += w * v; cn += w; }
    else           { const float w = wps[b * N + e]; sp += w * v; cp += w; }
  }
  const float wqp = expf(f1v), wqn = expf(ALPHA * f1v);
  const float denom = wqp * cp + wqn * cn;
  float val = (wqp * sp + wqn * sn) / denom + bias[d];
  out[(size_t)row * D + d] = val >= 0.f ? val : ALPHA * val;
}

extern "C" void kernel_launch(void* const* d_in, const int* in_sizes, int n_in,
                              void* d_out, int out_size, void* d_ws, size_t ws_size,
                              hipStream_t stream) {
  const float* seq  = (const float*)d_in[0];
  const float* Wf   = (const float*)d_in[1];
  const float* w1   = (const float*)d_in[2];
  const float* b1   = (const float*)d_in[3];
  const float* w2   = (const float*)d_in[4];
  const float* b2   = (const float*)d_in[5];
  const float* bias = (const float*)d_in[6];
  float* out = (float*)d_out;

  char* ws = (char*)d_ws;
  size_t off = 0;
  auto alloc = [&](size_t bytes) -> void* {
    void* p = ws + off;
    off = (off + bytes + 255) & ~(size_t)255;
    return p;
  };

  float* fts    = (float*)alloc((size_t)M * D * 4);
  float* f1     = (float*)alloc((size_t)M * 4);
  float* f2     = (float*)alloc((size_t)M * 4);
  float* f2s    = (float*)alloc((size_t)M * 4);
  int*   idxs   = (int*)  alloc((size_t)M * 4);
  float* wps    = (float*)alloc((size_t)M * 4);
  float* wns    = (float*)alloc((size_t)M * 4);
  int*   bid    = (int*)  alloc((size_t)M * 4);
  int*   histcnt= (int*)  alloc((size_t)B * P * NB * 4);
  int*   bstart = (int*)  alloc((size_t)B * (NB + 1) * 4);
  unsigned* mmu = (unsigned*)alloc((size_t)B * 2 * 4);
  float* Wp     = (float*)alloc((size_t)B * NB * D * 4);
  float* Wn     = (float*)alloc((size_t)B * NB * D * 4);
  float* Cp     = (float*)alloc((size_t)B * NB * 4);
  float* Cn     = (float*)alloc((size_t)B * NB * 4);
  float* Gp     = (float*)alloc((size_t)B * NGRP * D * 4);
  float* Gn     = (float*)alloc((size_t)B * NGRP * D * 4);
  float* SGp    = (float*)alloc((size_t)B * NGRP * 4);
  float* SGn    = (float*)alloc((size_t)B * NGRP * 4);
  float* BPos   = (float*)alloc((size_t)B * NB * D * 4);
  float* BNeg   = (float*)alloc((size_t)B * NB * D * 4);
  float* CpB    = (float*)alloc((size_t)B * NB * 4);
  float* CnB    = (float*)alloc((size_t)B * NB * 4);

  hipLaunchKernelGGL(k_gemm,   dim3(M / 64),   dim3(256),  0, stream, seq, Wf, fts, mmu);
  hipLaunchKernelGGL(k_f1f2,   dim3(M / 4),    dim3(256),  0, stream, fts, w1, b1, w2, b2, f1, f2, mmu);
  hipLaunchKernelGGL(k_hist,   dim3(B * P),    dim3(256),  0, stream, f2, mmu, bid, histcnt);
  hipLaunchKernelGGL(k_bscan,  dim3(B),        dim3(1024), 0, stream, histcnt, bstart);
  hipLaunchKernelGGL(k_scatter,dim3(B * P),    dim3(256),  0, stream, f2, bid, histcnt, bstart, f2s, idxs, wps, wns);
  hipLaunchKernelGGL(k_bsum,   dim3(B * NBB),  dim3(128),  0, stream, fts, idxs, wps, wns, bstart, Wp, Wn, Cp, Cn);
  hipLaunchKernelGGL(k_gsumA,  dim3(B * NGRP), dim3(128),  0, stream, Wp, Wn, Cp, Cn, Gp, Gn, SGp, SGn);
  hipLaunchKernelGGL(k_gscanB, dim3(B),        dim3(128),  0, stream, Gp, Gn, SGp, SGn);
  hipLaunchKernelGGL(k_gscanC, dim3(B * NGRP), dim3(128),  0, stream, Wp, Wn, Cp, Cn, Gp, Gn, SGp, SGn,
                     BPos, BNeg, CpB, CnB);
  hipLaunchKernelGGL(k_query,  dim3(M),        dim3(128),  0, stream, f1, f2s, idxs, wps, wns, fts, bstart, mmu,
                     BPos, BNeg, CpB, CnB, bias, out);
}

// Round 4
// 137.165 us; speedup vs baseline: 1.6566x; 1.6566x over previous
//
#include <hip/hip_runtime.h>
#include <cstddef>

#define ALPHA 0.2f
constexpr int B = 2, N = 8192, F = 256, D = 128;
constexpr int M = B * N;
constexpr int NB = 2048;          // value buckets per batch
constexpr int SUB = 256;          // elements per sub-block for stable scatter
constexpr int P = N / SUB;        // 32 sub-blocks per batch
constexpr int GB = 8;             // buckets per k_bsum block
constexpr int NBB = NB / GB;      // 256 bsum blocks per batch
constexpr int GSZ = 64;           // buckets per scan group
constexpr int NGRP = NB / GSZ;    // 32 groups per batch
constexpr int FBLK = M / 4;       // k_f1f2 grid (4096)
constexpr int FPB = FBLK / B;     // f1f2 blocks per batch (2048)

// ---- monotone float<->uint encoding ----
__device__ inline unsigned fenc(float x) {
  unsigned u = __float_as_uint(x);
  return (u & 0x80000000u) ? ~u : (u | 0x80000000u);
}
__device__ inline float fdec(unsigned u) {
  return (u & 0x80000000u) ? __uint_as_float(u ^ 0x80000000u) : __uint_as_float(~u);
}
__device__ inline void bparams(const unsigned* __restrict__ mmu, int b, float& mn, float& scale) {
  mn = fdec(mmu[b * 2 + 0]);
  float mx = fdec(mmu[b * 2 + 1]);
  float range = mx - mn;
  scale = ((float)NB - 0.001f) / fmaxf(range, 1e-30f);
}
__device__ inline int bucket_of(float x, float mn, float scale) {
  int g = (int)((x - mn) * scale);
  return g < 0 ? 0 : (g > NB - 1 ? NB - 1 : g);
}

// ---------------- GEMM: fts[m][d] = sum_f seq[m][f] * Wf[f][d] ----------------
__global__ __launch_bounds__(256) void k_gemm(const float* __restrict__ seq,
                                              const float* __restrict__ Wf,
                                              float* __restrict__ fts) {
  __shared__ float As[64][36];
  __shared__ float Bs[32][128];
  const int m0 = blockIdx.x * 64;
  const int t = threadIdx.x;
  const int colg = t & 31;
  const int rowg = t >> 5;
  float acc[8][4];
#pragma unroll
  for (int r = 0; r < 8; ++r)
#pragma unroll
    for (int c = 0; c < 4; ++c) acc[r][c] = 0.f;

  for (int kc = 0; kc < F; kc += 32) {
#pragma unroll
    for (int it = 0; it < 2; ++it) {
      int f = t + it * 256;
      int row = f >> 3, wi = f & 7;
      const float4 v = *reinterpret_cast<const float4*>(
          &seq[(size_t)(m0 + row) * F + kc + wi * 4]);
      As[row][wi * 4 + 0] = v.x; As[row][wi * 4 + 1] = v.y;
      As[row][wi * 4 + 2] = v.z; As[row][wi * 4 + 3] = v.w;
    }
#pragma unroll
    for (int it = 0; it < 4; ++it) {
      int f = t + it * 256;
      int row = f >> 5, c4 = f & 31;
      *reinterpret_cast<float4*>(&Bs[row][c4 * 4]) =
          *reinterpret_cast<const float4*>(&Wf[(size_t)(kc + row) * D + c4 * 4]);
    }
    __syncthreads();
#pragma unroll
    for (int k = 0; k < 32; ++k) {
      float4 b4 = *reinterpret_cast<const float4*>(&Bs[k][colg * 4]);
#pragma unroll
      for (int r = 0; r < 8; ++r) {
        float a = As[rowg * 8 + r][k];
        acc[r][0] += a * b4.x; acc[r][1] += a * b4.y;
        acc[r][2] += a * b4.z; acc[r][3] += a * b4.w;
      }
    }
    __syncthreads();
  }
#pragma unroll
  for (int r = 0; r < 8; ++r) {
    float4 v = {acc[r][0], acc[r][1], acc[r][2], acc[r][3]};
    *reinterpret_cast<float4*>(&fts[(size_t)(m0 + rowg * 8 + r) * D + colg * 4]) = v;
  }
}

// ---------------- f1/f2 + per-block partial min/max (no atomics) ----------------
__global__ __launch_bounds__(256) void k_f1f2(const float* __restrict__ fts,
                                              const float* __restrict__ w1,
                                              const float* __restrict__ b1,
                                              const float* __restrict__ w2,
                                              const float* __restrict__ b2,
                                              float* __restrict__ f1,
                                              float* __restrict__ f2,
                                              unsigned* __restrict__ pmn,
                                              unsigned* __restrict__ pmx) {
  __shared__ unsigned redmn[4], redmx[4];
  const int wid = threadIdx.x >> 6;
  const int lane = threadIdx.x & 63;
  const int row = blockIdx.x * 4 + wid;
  const float* p = &fts[(size_t)row * D];
  float x0 = p[lane], x1 = p[lane + 64];
  float d1 = x0 * w1[lane] + x1 * w1[lane + 64];
  float d2 = x0 * w2[lane] + x1 * w2[lane + 64];
#pragma unroll
  for (int off = 32; off > 0; off >>= 1) {
    d1 += __shfl_down(d1, off);
    d2 += __shfl_down(d2, off);
  }
  if (lane == 0) {
    f1[row] = d1 + b1[0];
    float v2 = d2 + b2[0];
    f2[row] = v2;
    unsigned e = fenc(v2);
    redmn[wid] = e; redmx[wid] = e;
  }
  __syncthreads();
  if (threadIdx.x == 0) {
    pmn[blockIdx.x] = min(min(redmn[0], redmn[1]), min(redmn[2], redmn[3]));
    pmx[blockIdx.x] = max(max(redmx[0], redmx[1]), max(redmx[2], redmx[3]));
  }
}

// ---------------- reduce per-block partials -> mmu (no atomics) ----------------
__global__ __launch_bounds__(1024) void k_mmred(const unsigned* __restrict__ pmn,
                                                const unsigned* __restrict__ pmx,
                                                unsigned* __restrict__ mmu) {
  __shared__ unsigned smn[1024], smx[1024];
  const int b = blockIdx.x, t = threadIdx.x;
  unsigned mn = pmn[b * FPB + t], mx = pmx[b * FPB + t];
  mn = min(mn, pmn[b * FPB + t + 1024]);
  mx = max(mx, pmx[b * FPB + t + 1024]);
  smn[t] = mn; smx[t] = mx;
  __syncthreads();
  for (int s = 512; s > 0; s >>= 1) {
    if (t < s) {
      smn[t] = min(smn[t], smn[t + s]);
      smx[t] = max(smx[t], smx[t + s]);
    }
    __syncthreads();
  }
  if (t == 0) { mmu[b * 2 + 0] = smn[0]; mmu[b * 2 + 1] = smx[0]; }
}

// ---------------- per-sub-block histogram (deterministic) ----------------
__global__ __launch_bounds__(256) void k_hist(const float* __restrict__ f2,
                                              const unsigned* __restrict__ mmu,
                                              int* __restrict__ bid,
                                              int* __restrict__ histcnt) {
  __shared__ int hist[NB];
  const int b = blockIdx.x / P, p = blockIdx.x % P;
  const int t = threadIdx.x;
  for (int i = t; i < NB; i += 256) hist[i] = 0;
  float mn, scale; bparams(mmu, b, mn, scale);
  const int j = p * SUB + t;
  float x = f2[b * N + j];
  int g = bucket_of(x, mn, scale);
  bid[b * N + j] = g;
  __syncthreads();
  atomicAdd(&hist[g], 1);
  __syncthreads();
  for (int i = t; i < NB; i += 256)
    histcnt[((size_t)(b * P + p)) * NB + i] = hist[i];
}

// ---------------- bucket-count reduce + exclusive Blelloch scan ----------------
__global__ __launch_bounds__(1024) void k_bscan(const int* __restrict__ histcnt,
                                                int* __restrict__ bstart) {
  __shared__ int s[NB];
  const int b = blockIdx.x, t = threadIdx.x;
  int c0 = 0, c1 = 0;
  const int g0 = 2 * t, g1 = 2 * t + 1;
  for (int p = 0; p < P; ++p) {
    const int* h = &histcnt[((size_t)(b * P + p)) * NB];
    c0 += h[g0]; c1 += h[g1];
  }
  s[g0] = c0; s[g1] = c1;
  int offset = 1;
  for (int d = NB >> 1; d > 0; d >>= 1) {
    __syncthreads();
    if (t < d) { int ai = offset * (2 * t + 1) - 1, bi = offset * (2 * t + 2) - 1; s[bi] += s[ai]; }
    offset <<= 1;
  }
  __syncthreads();
  if (t == 0) { bstart[b * (NB + 1) + NB] = s[NB - 1]; s[NB - 1] = 0; }
  for (int d = 1; d < NB; d <<= 1) {
    offset >>= 1;
    __syncthreads();
    if (t < d) {
      int ai = offset * (2 * t + 1) - 1, bi = offset * (2 * t + 2) - 1;
      int tmp = s[ai]; s[ai] = s[bi]; s[bi] += tmp;
    }
  }
  __syncthreads();
  bstart[b * (NB + 1) + g0] = s[g0];
  bstart[b * (NB + 1) + g1] = s[g1];
}

// ---------------- stable deterministic scatter + weight precompute ----------------
__global__ __launch_bounds__(256) void k_scatter(const float* __restrict__ f2,
                                                 const int* __restrict__ bid,
                                                 const int* __restrict__ histcnt,
                                                 const int* __restrict__ bstart,
                                                 float* __restrict__ f2s,
                                                 int* __restrict__ idxs,
                                                 float* __restrict__ wps,
                                                 float* __restrict__ wns) {
  __shared__ int bids[SUB];
  const int b = blockIdx.x / P, p = blockIdx.x % P;
  const int t = threadIdx.x;
  const int j = p * SUB + t;
  const int g = bid[b * N + j];
  bids[t] = g;
  __syncthreads();
  int off = bstart[b * (NB + 1) + g];
  for (int pp = 0; pp < p; ++pp) off += histcnt[((size_t)(b * P + pp)) * NB + g];
  for (int jj = 0; jj < t; ++jj) off += (bids[jj] == g);
  const float x = f2[b * N + j];
  f2s[b * N + off] = x;
  idxs[b * N + off] = j;
  wps[b * N + off] = expf(x);
  wns[b * N + off] = expf(ALPHA * x);
}

// ---------------- per-bucket weighted sums (segmented, deterministic) ----------------
__global__ __launch_bounds__(128) void k_bsum(const float* __restrict__ fts,
                                              const int* __restrict__ idxs,
                                              const float* __restrict__ wps,
                                              const float* __restrict__ wns,
                                              const int* __restrict__ bstart,
                                              float* __restrict__ Wp, float* __restrict__ Wn,
                                              float* __restrict__ Cp, float* __restrict__ Cn) {
  const int b = blockIdx.x / NBB, blk = blockIdx.x % NBB;
  const int d = threadIdx.x;
  const int gbase = blk * GB;
  for (int gg = 0; gg < GB; ++gg) {
    const int g = gbase + gg;
    const int e0 = bstart[b * (NB + 1) + g], e1 = bstart[b * (NB + 1) + g + 1];
    float ap = 0.f, an = 0.f, sp = 0.f, sn = 0.f;
    for (int e = e0; e < e1; ++e) {
      const int j = idxs[b * N + e];
      const float v = fts[((size_t)b * N + j) * D + d];
      const float wp = wps[b * N + e], wn = wns[b * N + e];
      ap += wp * v; an += wn * v; sp += wp; sn += wn;
    }
    Wp[((size_t)b * NB + g) * D + d] = ap;
    Wn[((size_t)b * NB + g) * D + d] = an;
    if (d == 0) { Cp[b * NB + g] = sp; Cn[b * NB + g] = sn; }
  }
}

// ---------------- group sums (64 buckets per group) ----------------
__global__ __launch_bounds__(128) void k_gsumA(const float* __restrict__ Wp, const float* __restrict__ Wn,
                                               const float* __restrict__ Cp, const float* __restrict__ Cn,
                                               float* __restrict__ Gp, float* __restrict__ Gn,
                                               float* __restrict__ SGp, float* __restrict__ SGn) {
  const int b = blockIdx.x / NGRP, grp = blockIdx.x % NGRP;
  const int d = threadIdx.x;
  float sp = 0.f, sn = 0.f, cp = 0.f, cn = 0.f;
  for (int gg = 0; gg < GSZ; ++gg) {
    const int g = grp * GSZ + gg;
    sp += Wp[((size_t)b * NB + g) * D + d];
    sn += Wn[((size_t)b * NB + g) * D + d];
    if (d == 0) { cp += Cp[b * NB + g]; cn += Cn[b * NB + g]; }
  }
  Gp[((size_t)b * NGRP + grp) * D + d] = sp;
  Gn[((size_t)b * NGRP + grp) * D + d] = sn;
  if (d == 0) { SGp[b * NGRP + grp] = cp; SGn[b * NGRP + grp] = cn; }
}

// ---------------- scan the 32 group sums ----------------
__global__ __launch_bounds__(128) void k_gscanB(float* __restrict__ Gp, float* __restrict__ Gn,
                                                float* __restrict__ SGp, float* __restrict__ SGn) {
  const int b = blockIdx.x, d = threadIdx.x;
  float run = 0.f;
  for (int grp = 0; grp < NGRP; ++grp) {
    float t = Gn[((size_t)b * NGRP + grp) * D + d];
    Gn[((size_t)b * NGRP + grp) * D + d] = run; run += t;
  }
  run = 0.f;
  for (int grp = NGRP - 1; grp >= 0; --grp) {
    float t = Gp[((size_t)b * NGRP + grp) * D + d];
    Gp[((size_t)b * NGRP + grp) * D + d] = run; run += t;
  }
  if (d == 0) {
    float r = 0.f;
    for (int grp = 0; grp < NGRP; ++grp) { float t = SGn[b * NGRP + grp]; SGn[b * NGRP + grp] = r; r += t; }
    r = 0.f;
    for (int grp = NGRP - 1; grp >= 0; --grp) { float t = SGp[b * NGRP + grp]; SGp[b * NGRP + grp] = r; r += t; }
  }
}

// ---------------- within-group exclusive scans -> bucket-boundary sums ----------------
__global__ __launch_bounds__(128) void k_gscanC(const float* __restrict__ Wp, const float* __restrict__ Wn,
                                                const float* __restrict__ Cp, const float* __restrict__ Cn,
                                                const float* __restrict__ Gp, const float* __restrict__ Gn,
                                                const float* __restrict__ SGp, const float* __restrict__ SGn,
                                                float* __restrict__ BPos, float* __restrict__ BNeg,
                                                float* __restrict__ CpB, float* __restrict__ CnB) {
  const int b = blockIdx.x / NGRP, grp = blockIdx.x % NGRP;
  const int d = threadIdx.x;
  float runn = Gn[((size_t)b * NGRP + grp) * D + d];
  for (int gg = 0; gg < GSZ; ++gg) {
    const int g = grp * GSZ + gg;
    BNeg[((size_t)b * NB + g) * D + d] = runn;
    runn += Wn[((size_t)b * NB + g) * D + d];
  }
  float runp = Gp[((size_t)b * NGRP + grp) * D + d];
  for (int gg = GSZ - 1; gg >= 0; --gg) {
    const int g = grp * GSZ + gg;
    BPos[((size_t)b * NB + g) * D + d] = runp;
    runp += Wp[((size_t)b * NB + g) * D + d];
  }
  if (d == 0) {
    float r = SGn[b * NGRP + grp];
    for (int gg = 0; gg < GSZ; ++gg) { const int g = grp * GSZ + gg; CnB[b * NB + g] = r; r += Cn[b * NB + g]; }
    r = SGp[b * NGRP + grp];
    for (int gg = GSZ - 1; gg >= 0; --gg) { const int g = grp * GSZ + gg; CpB[b * NB + g] = r; r += Cp[b * NB + g]; }
  }
}

// ---------------- query ----------------
__global__ __launch_bounds__(128) void k_query(const float* __restrict__ f1,
                                               const float* __restrict__ f2s,
                                               const int* __restrict__ idxs,
                                               const float* __restrict__ wps,
                                               const float* __restrict__ wns,
                                               const float* __restrict__ fts,
                                               const int* __restrict__ bstart,
                                               const unsigned* __restrict__ mmu,
                                               const float* __restrict__ BPos, const float* __restrict__ BNeg,
                                               const float* __restrict__ CpB, const float* __restrict__ CnB,
                                               const float* __restrict__ bias,
                                               float* __restrict__ out) {
  const int row = blockIdx.x;  // b*N + i
  const int b = row / N;
  const int d = threadIdx.x;
  const float f1v = f1[row];
  const float th = -f1v;
  float mn, scale; bparams(mmu, b, mn, scale);
  const int g = bucket_of(th, mn, scale);
  const int base = bstart[b * (NB + 1) + g];
  const int end  = bstart[b * (NB + 1) + g + 1];
  float sn = BNeg[((size_t)b * NB + g) * D + d];
  float sp = BPos[((size_t)b * NB + g) * D + d];
  float cn = CnB[b * NB + g];
  float cp = CpB[b * NB + g];
  for (int e = base; e < end; ++e) {
    const float key = f2s[b * N + e];
    const int j = idxs[b * N + e];
    const float v = fts[((size_t)b * N + j) * D + d];
    if (key <= th) { const float w = wns[b * N + e]; sn += w * v; cn += w; }
    else           { const float w = wps[b * N + e]; sp += w * v; cp += w; }
  }
  const float wqp = expf(f1v), wqn = expf(ALPHA * f1v);
  const float denom = wqp * cp + wqn * cn;
  float val = (wqp * sp + wqn * sn) / denom + bias[d];
  out[(size_t)row * D + d] = val >= 0.f ? val : ALPHA * val;
}

extern "C" void kernel_launch(void* const* d_in, const int* in_sizes, int n_in,
                              void* d_out, int out_size, void* d_ws, size_t ws_size,
                              hipStream_t stream) {
  const float* seq  = (const float*)d_in[0];
  const float* Wf   = (const float*)d_in[1];
  const float* w1   = (const float*)d_in[2];
  const float* b1   = (const float*)d_in[3];
  const float* w2   = (const float*)d_in[4];
  const float* b2   = (const float*)d_in[5];
  const float* bias = (const float*)d_in[6];
  float* out = (float*)d_out;

  char* ws = (char*)d_ws;
  size_t off = 0;
  auto alloc = [&](size_t bytes) -> void* {
    void* p = ws + off;
    off = (off + bytes + 255) & ~(size_t)255;
    return p;
  };

  float* fts    = (float*)alloc((size_t)M * D * 4);
  float* f1     = (float*)alloc((size_t)M * 4);
  float* f2     = (float*)alloc((size_t)M * 4);
  float* f2s    = (float*)alloc((size_t)M * 4);
  int*   idxs   = (int*)  alloc((size_t)M * 4);
  float* wps    = (float*)alloc((size_t)M * 4);
  float* wns    = (float*)alloc((size_t)M * 4);
  int*   bid    = (int*)  alloc((size_t)M * 4);
  int*   histcnt= (int*)  alloc((size_t)B * P * NB * 4);
  int*   bstart = (int*)  alloc((size_t)B * (NB + 1) * 4);
  unsigned* mmu = (unsigned*)alloc((size_t)B * 2 * 4);
  unsigned* pmn = (unsigned*)alloc((size_t)FBLK * 4);
  unsigned* pmx = (unsigned*)alloc((size_t)FBLK * 4);
  float* Wp     = (float*)alloc((size_t)B * NB * D * 4);
  float* Wn     = (float*)alloc((size_t)B * NB * D * 4);
  float* Cp     = (float*)alloc((size_t)B * NB * 4);
  float* Cn     = (float*)alloc((size_t)B * NB * 4);
  float* Gp     = (float*)alloc((size_t)B * NGRP * D * 4);
  float* Gn     = (float*)alloc((size_t)B * NGRP * D * 4);
  float* SGp    = (float*)alloc((size_t)B * NGRP * 4);
  float* SGn    = (float*)alloc((size_t)B * NGRP * 4);
  float* BPos   = (float*)alloc((size_t)B * NB * D * 4);
  float* BNeg   = (float*)alloc((size_t)B * NB * D * 4);
  float* CpB    = (float*)alloc((size_t)B * NB * 4);
  float* CnB    = (float*)alloc((size_t)B * NB * 4);

  hipLaunchKernelGGL(k_gemm,   dim3(M / 64),   dim3(256),  0, stream, seq, Wf, fts);
  hipLaunchKernelGGL(k_f1f2,   dim3(FBLK),     dim3(256),  0, stream, fts, w1, b1, w2, b2, f1, f2, pmn, pmx);
  hipLaunchKernelGGL(k_mmred,  dim3(B),        dim3(1024), 0, stream, pmn, pmx, mmu);
  hipLaunchKernelGGL(k_hist,   dim3(B * P),    dim3(256),  0, stream, f2, mmu, bid, histcnt);
  hipLaunchKernelGGL(k_bscan,  dim3(B),        dim3(1024), 0, stream, histcnt, bstart);
  hipLaunchKernelGGL(k_scatter,dim3(B * P),    dim3(256),  0, stream, f2, bid, histcnt, bstart, f2s, idxs, wps, wns);
  hipLaunchKernelGGL(k_bsum,   dim3(B * NBB),  dim3(128),  0, stream, fts, idxs, wps, wns, bstart, Wp, Wn, Cp, Cn);
  hipLaunchKernelGGL(k_gsumA,  dim3(B * NGRP), dim3(128),  0, stream, Wp, Wn, Cp, Cn, Gp, Gn, SGp, SGn);
  hipLaunchKernelGGL(k_gscanB, dim3(B),        dim3(128),  0, stream, Gp, Gn, SGp, SGn);
  hipLaunchKernelGGL(k_gscanC, dim3(B * NGRP), dim3(128),  0, stream, Wp, Wn, Cp, Cn, Gp, Gn, SGp, SGn,
                     BPos, BNeg, CpB, CnB);
  hipLaunchKernelGGL(k_query,  dim3(M),        dim3(128),  0, stream, f1, f2s, idxs, wps, wns, fts, bstart, mmu,
                     BPos, BNeg, CpB, CnB, bias, out);
}